// Round 1
// baseline (6207.281 us; speedup 1.0000x reference)
//
#include <hip/hip_runtime.h>
#include <cstddef>

#define BATCH 512
#define ESZ   256
#define HSZ   512
#define G4    2048      // 4*HS
#define SRCL  64
#define TRGL  48
#define ODIM  67
#define DECM  (47*512)  // 24064 decoder rows

__device__ __forceinline__ float sigm(float x) { return 1.0f / (1.0f + expf(-x)); }

// ---------------- embedding gather: out[row] = table[tok[row]] ----------------
__global__ void embed_kernel(const int* __restrict__ tok, const float* __restrict__ table,
                             float* __restrict__ out, int n_rows) {
    int i = blockIdx.x * 256 + threadIdx.x;   // one float4 per thread
    int row = i >> 6;                          // 64 float4 per 256-wide row
    if (row >= n_rows) return;
    int e4 = (i & 63) << 2;
    int t = tok[row];
    *(float4*)(out + (size_t)row * ESZ + e4) =
        *(const float4*)(table + (size_t)t * ESZ + e4);
}

__global__ void zero_kernel(float* __restrict__ p, int n) {
    int i = blockIdx.x * 256 + threadIdx.x;
    if (i < n) p[i] = 0.f;
}

// bias folds: bih+bhh for enc_f, enc_b, dec
__global__ void bias_prep(const float* __restrict__ af, const float* __restrict__ bf,
                          const float* __restrict__ ab, const float* __restrict__ bb,
                          const float* __restrict__ ad, const float* __restrict__ bd,
                          float* __restrict__ of, float* __restrict__ ob, float* __restrict__ od) {
    int i = blockIdx.x * 256 + threadIdx.x;
    if (i < G4) { of[i] = af[i] + bf[i]; ob[i] = ab[i] + bb[i]; od[i] = ad[i] + bd[i]; }
}

// ---------------- generic fp32 GEMM core ----------------
// C[M x N] = [A1|A2] (M x (K1+K2), row-major) * [B1|B2]^T  (+bias) (+C if add_c)
// B rows are N; ldb strides. K1,K2 multiples of 16; M multiple of 64. N guarded.
__device__ __forceinline__ void gemm_core(
    float (*As)[64], float (*Bs)[64],
    const float* __restrict__ A1, int lda1,
    const float* __restrict__ A2, int lda2,
    const float* __restrict__ B1, int ldb1,
    const float* __restrict__ B2, int ldb2,
    int K1, int K2,
    const float* __restrict__ bias,
    float* __restrict__ C, int ldc, int N, int add_c,
    int m0, int n0)
{
    const int tid = threadIdx.x;
    const int tm = (tid >> 4) << 2;   // 0..60
    const int tn = (tid & 15) << 2;   // 0..60
    const int lr = tid >> 2;          // 0..63
    const int lk = (tid & 3) << 2;    // 0,4,8,12
    float acc[4][4] = {};
    const int K = K1 + K2;
    for (int kt = 0; kt < K; kt += 16) {
        const float* Ap; const float* Bp; int kc, lda, ldb;
        if (kt < K1) { Ap = A1; Bp = B1; kc = kt;      lda = lda1; ldb = ldb1; }
        else         { Ap = A2; Bp = B2; kc = kt - K1; lda = lda2; ldb = ldb2; }
        float4 va = *(const float4*)(Ap + (size_t)(m0 + lr) * lda + kc + lk);
        As[lk + 0][lr] = va.x; As[lk + 1][lr] = va.y;
        As[lk + 2][lr] = va.z; As[lk + 3][lr] = va.w;
        int gn = n0 + lr;
        float4 vb = make_float4(0.f, 0.f, 0.f, 0.f);
        if (gn < N) vb = *(const float4*)(Bp + (size_t)gn * ldb + kc + lk);
        Bs[lk + 0][lr] = vb.x; Bs[lk + 1][lr] = vb.y;
        Bs[lk + 2][lr] = vb.z; Bs[lk + 3][lr] = vb.w;
        __syncthreads();
#pragma unroll
        for (int kk = 0; kk < 16; ++kk) {
            float a0 = As[kk][tm + 0], a1 = As[kk][tm + 1];
            float a2 = As[kk][tm + 2], a3 = As[kk][tm + 3];
            float w0 = Bs[kk][tn + 0], w1 = Bs[kk][tn + 1];
            float w2 = Bs[kk][tn + 2], w3 = Bs[kk][tn + 3];
            acc[0][0] += a0 * w0; acc[0][1] += a0 * w1; acc[0][2] += a0 * w2; acc[0][3] += a0 * w3;
            acc[1][0] += a1 * w0; acc[1][1] += a1 * w1; acc[1][2] += a1 * w2; acc[1][3] += a1 * w3;
            acc[2][0] += a2 * w0; acc[2][1] += a2 * w1; acc[2][2] += a2 * w2; acc[2][3] += a2 * w3;
            acc[3][0] += a3 * w0; acc[3][1] += a3 * w1; acc[3][2] += a3 * w2; acc[3][3] += a3 * w3;
        }
        __syncthreads();
    }
#pragma unroll
    for (int mi = 0; mi < 4; ++mi) {
        int m = m0 + tm + mi;
#pragma unroll
        for (int jj = 0; jj < 4; ++jj) {
            int n = n0 + tn + jj;
            if (n < N) {
                float v = acc[mi][jj];
                if (bias) v += bias[n];
                size_t ci = (size_t)m * ldc + n;
                if (add_c) v += C[ci];
                C[ci] = v;
            }
        }
    }
}

__global__ __launch_bounds__(256) void gemm2_kernel(
    const float* A1, int lda1, const float* A2, int lda2,
    const float* B1, int ldb1, const float* B2, int ldb2,
    int K1, int K2, const float* bias, float* C, int ldc, int N, int add_c)
{
    __shared__ float As[16][64];
    __shared__ float Bs[16][64];
    gemm_core(As, Bs, A1, lda1, A2, lda2, B1, ldb1, B2, ldb2, K1, K2,
              bias, C, ldc, N, add_c, blockIdx.y * 64, blockIdx.x * 64);
}

// ---------------- encoder step: gates = [emb_t | h] @ [Wih | Whh]^T + bias ----------------
__global__ __launch_bounds__(256) void enc_step_gemm(
    const float* __restrict__ emb_e, int t,
    const float* __restrict__ h_f, const float* __restrict__ h_b,
    const float* __restrict__ Wih_f, const float* __restrict__ Whh_f,
    const float* __restrict__ Wih_b, const float* __restrict__ Whh_b,
    const float* __restrict__ bias_f, const float* __restrict__ bias_b,
    float* __restrict__ gates)
{
    __shared__ float As[16][64];
    __shared__ float Bs[16][64];
    int dir = blockIdx.z;
    int tt = dir ? (SRCL - 1 - t) : t;
    const float* A1 = emb_e + (size_t)tt * BATCH * ESZ;
    const float* A2 = dir ? h_b : h_f;
    const float* W1 = dir ? Wih_b : Wih_f;
    const float* W2 = dir ? Whh_b : Whh_f;
    const float* bs = dir ? bias_b : bias_f;
    float* C = gates + (size_t)dir * BATCH * G4;
    gemm_core(As, Bs, A1, ESZ, A2, HSZ, W1, ESZ, W2, HSZ, ESZ, HSZ,
              bs, C, G4, G4, 0, blockIdx.y * 64, blockIdx.x * 64);
}

// encoder LSTM pointwise: update h,c in place, scatter h into encoder_states
__global__ void enc_elem(const float* __restrict__ gates,
                         float* __restrict__ h_f, float* __restrict__ c_f,
                         float* __restrict__ h_b, float* __restrict__ c_b,
                         float* __restrict__ es, int t)
{
    int dir = blockIdx.y;
    int i = blockIdx.x * 256 + threadIdx.x;   // 0 .. B*HS-1
    int b = i >> 9, j = i & 511;
    const float* g = gates + (size_t)dir * BATCH * G4 + (size_t)b * G4;
    float gi = g[j], gf = g[HSZ + j], gg = g[2 * HSZ + j], go = g[3 * HSZ + j];
    float* hp = dir ? h_b : h_f;
    float* cp = dir ? c_b : c_f;
    float c = sigm(gf) * cp[i & (BATCH * HSZ - 1)] + sigm(gi) * tanhf(gg);
    // note: i == b*512+j already
    c = sigm(gf) * 0.f;  // placeholder removed below
    (void)c;
    float cprev = cp[(size_t)b * HSZ + j];
    float cnew = sigm(gf) * cprev + sigm(gi) * tanhf(gg);
    float hnew = sigm(go) * tanhf(cnew);
    cp[(size_t)b * HSZ + j] = cnew;
    hp[(size_t)b * HSZ + j] = hnew;
    int s = dir ? (SRCL - 1 - t) : t;
    es[((size_t)s * BATCH + b) * (2 * HSZ) + dir * HSZ + j] = hnew;
}

// eh[b] = dot(energy_W[0:512], hidden_h[b]) + energy_b
__global__ void eh_kernel(const float* __restrict__ hid_h, const float* __restrict__ eW,
                          const float* __restrict__ eb, float* __restrict__ eh) {
    int w = blockIdx.x * 4 + (threadIdx.x >> 6);
    int lane = threadIdx.x & 63;
    if (w >= BATCH) return;
    float s = 0.f;
    for (int k = lane; k < HSZ; k += 64) s += hid_h[(size_t)w * HSZ + k] * eW[k];
    for (int off = 32; off; off >>= 1) s += __shfl_down(s, off);
    if (lane == 0) eh[w] = s + eb[0];
}

// energy[s][b] = relu(eh[b] + dot(energy_W[512:1536], es[s][b][:]))
__global__ void energy_kernel(const float* __restrict__ es, const float* __restrict__ eW2,
                              const float* __restrict__ eh, float* __restrict__ energy) {
    int w = blockIdx.x * 4 + (threadIdx.x >> 6);   // 0 .. S*B-1
    int lane = threadIdx.x & 63;
    int s = w >> 9, b = w & 511;
    const float* row = es + ((size_t)s * BATCH + b) * (2 * HSZ);
    float v = 0.f;
    for (int k = lane; k < 2 * HSZ; k += 64) v += row[k] * eW2[k];
    for (int off = 32; off; off >>= 1) v += __shfl_down(v, off);
    if (lane == 0) energy[(size_t)s * BATCH + b] = fmaxf(v + eh[b], 0.f);
}

// softmax over s (=64 = wave size) per column b
__global__ void softmax_kernel(const float* __restrict__ energy, float* __restrict__ attn) {
    int b = blockIdx.x * 4 + (threadIdx.x >> 6);
    int lane = threadIdx.x & 63;                    // lane = s
    if (b >= BATCH) return;
    float v = energy[(size_t)lane * BATCH + b];
    float m = v;
    for (int off = 32; off; off >>= 1) m = fmaxf(m, __shfl_xor(m, off));
    float e = expf(v - m);
    float sum = e;
    for (int off = 32; off; off >>= 1) sum += __shfl_xor(sum, off);
    attn[(size_t)lane * BATCH + b] = e / sum;
}

// context[b][j] = sum_s attn[s][b] * es[s][b][j]
__global__ void context_kernel(const float* __restrict__ attn, const float* __restrict__ es,
                               float* __restrict__ ctx) {
    int b = blockIdx.x;
    int j = threadIdx.x * 4;
    float4 acc = make_float4(0.f, 0.f, 0.f, 0.f);
    for (int s = 0; s < SRCL; ++s) {
        float a = attn[(size_t)s * BATCH + b];
        float4 v = *(const float4*)(es + ((size_t)s * BATCH + b) * (2 * HSZ) + j);
        acc.x += a * v.x; acc.y += a * v.y; acc.z += a * v.z; acc.w += a * v.w;
    }
    *(float4*)(ctx + (size_t)b * (2 * HSZ) + j) = acc;
}

// ---------------- decoder: fused gates-GEMM + LSTM pointwise ----------------
// For rows m = t*B+b (M=24064) and j-tile of 64:
//   gate_g[m][j] = emb_d[m] . dec_Wih[g*512+j][1024:1280] + D0[b][g*512+j]
//   h_new[m][j]  = sig(o)*tanh( sig(f)*hidden_c[b][j] + sig(i)*tanh(g) )
__global__ __launch_bounds__(256) void dec_fused(
    const float* __restrict__ emb_d, const float* __restrict__ dec_Wih,
    const float* __restrict__ D0, const float* __restrict__ hid_c,
    float* __restrict__ h_new)
{
    __shared__ float As[16][64];
    __shared__ float Bs[4][16][64];
    const int m0 = blockIdx.y * 64;
    const int j0 = blockIdx.x * 64;
    const int tid = threadIdx.x;
    const int tm = (tid >> 4) << 2;
    const int tn = (tid & 15) << 2;
    const int lr = tid >> 2;
    const int lk = (tid & 3) << 2;
    float acc[4][4][4] = {};   // [gate][mi][jj]
    for (int kt = 0; kt < ESZ; kt += 16) {
        float4 va = *(const float4*)(emb_d + (size_t)(m0 + lr) * ESZ + kt + lk);
        As[lk + 0][lr] = va.x; As[lk + 1][lr] = va.y;
        As[lk + 2][lr] = va.z; As[lk + 3][lr] = va.w;
#pragma unroll
        for (int g = 0; g < 4; ++g) {
            int gn = g * HSZ + j0 + lr;
            float4 vb = *(const float4*)(dec_Wih + (size_t)gn * (2 * HSZ + ESZ) + (2 * HSZ) + kt + lk);
            Bs[g][lk + 0][lr] = vb.x; Bs[g][lk + 1][lr] = vb.y;
            Bs[g][lk + 2][lr] = vb.z; Bs[g][lk + 3][lr] = vb.w;
        }
        __syncthreads();
#pragma unroll
        for (int kk = 0; kk < 16; ++kk) {
            float a[4];
#pragma unroll
            for (int mi = 0; mi < 4; ++mi) a[mi] = As[kk][tm + mi];
#pragma unroll
            for (int g = 0; g < 4; ++g) {
                float w0 = Bs[g][kk][tn + 0], w1 = Bs[g][kk][tn + 1];
                float w2 = Bs[g][kk][tn + 2], w3 = Bs[g][kk][tn + 3];
#pragma unroll
                for (int mi = 0; mi < 4; ++mi) {
                    acc[g][mi][0] += a[mi] * w0;
                    acc[g][mi][1] += a[mi] * w1;
                    acc[g][mi][2] += a[mi] * w2;
                    acc[g][mi][3] += a[mi] * w3;
                }
            }
        }
        __syncthreads();
    }
#pragma unroll
    for (int mi = 0; mi < 4; ++mi) {
        int m = m0 + tm + mi;
        int b = m & (BATCH - 1);
#pragma unroll
        for (int jj = 0; jj < 4; ++jj) {
            int j = j0 + tn + jj;
            const float* d0 = D0 + (size_t)b * G4;
            float gi = acc[0][mi][jj] + d0[j];
            float gf = acc[1][mi][jj] + d0[HSZ + j];
            float gg = acc[2][mi][jj] + d0[2 * HSZ + j];
            float go = acc[3][mi][jj] + d0[3 * HSZ + j];
            float cnew = sigm(gf) * hid_c[(size_t)b * HSZ + j] + sigm(gi) * tanhf(gg);
            h_new[(size_t)m * HSZ + j] = sigm(go) * tanhf(cnew);
        }
    }
}

// ---------------- launch ----------------
extern "C" void kernel_launch(void* const* d_in, const int* in_sizes, int n_in,
                              void* d_out, int out_size, void* d_ws, size_t ws_size,
                              hipStream_t stream) {
    const int*   src      = (const int*)d_in[0];
    const int*   trg      = (const int*)d_in[1];
    const float* enc_emb  = (const float*)d_in[2];
    const float* Wih_f    = (const float*)d_in[3];
    const float* Whh_f    = (const float*)d_in[4];
    const float* bih_f    = (const float*)d_in[5];
    const float* bhh_f    = (const float*)d_in[6];
    const float* Wih_b    = (const float*)d_in[7];
    const float* Whh_b    = (const float*)d_in[8];
    const float* bih_b    = (const float*)d_in[9];
    const float* bhh_b    = (const float*)d_in[10];
    const float* fc_h_W   = (const float*)d_in[11];
    const float* fc_h_b   = (const float*)d_in[12];
    const float* fc_c_W   = (const float*)d_in[13];
    const float* fc_c_b   = (const float*)d_in[14];
    const float* dec_emb  = (const float*)d_in[15];
    const float* dec_Wih  = (const float*)d_in[16];
    const float* dec_Whh  = (const float*)d_in[17];
    const float* dec_bih  = (const float*)d_in[18];
    const float* dec_bhh  = (const float*)d_in[19];
    const float* energy_W = (const float*)d_in[20];
    const float* energy_b = (const float*)d_in[21];
    const float* fc_out_W = (const float*)d_in[22];
    const float* fc_out_b = (const float*)d_in[23];
    float* out = (float*)d_out;

    // workspace layout (floats)
    float* ws     = (float*)d_ws;
    float* emb_e  = ws;                         // 64*512*256   = 8388608
    float* emb_d  = emb_e + 8388608;            // 47*512*256   = 6160384
    float* es     = emb_d + 6160384;            // 64*512*1024  = 33554432
    float* h_f    = es + 33554432;              // 262144
    float* c_f    = h_f + 262144;
    float* h_b    = c_f + 262144;
    float* c_b    = h_b + 262144;
    float* gates  = c_b + 262144;               // 2*512*2048   = 2097152
    float* hid_h  = gates + 2097152;            // 262144
    float* hid_c  = hid_h + 262144;
    float* ehv    = hid_c + 262144;             // 512
    float* energy = ehv + 512;                  // 32768
    float* attn   = energy + 32768;             // 32768
    float* ctx    = attn + 32768;               // 524288
    float* D0     = ctx + 524288;               // 1048576
    float* bias_f = D0 + 1048576;               // 2048
    float* bias_b = bias_f + 2048;              // 2048
    float* bias_d = bias_b + 2048;              // 2048
    float* h_new  = bias_d + 2048;              // 47*512*512 = 12320768
    // total ~263 MB

    // embeddings
    embed_kernel<<<8192, 256, 0, stream>>>(src, enc_emb, emb_e, SRCL * BATCH);
    embed_kernel<<<6016, 256, 0, stream>>>(trg, dec_emb, emb_d, (TRGL - 1) * BATCH);
    // zero h/c (contiguous 4*512*512)
    zero_kernel<<<4096, 256, 0, stream>>>(h_f, 4 * BATCH * HSZ);
    bias_prep<<<8, 256, 0, stream>>>(bih_f, bhh_f, bih_b, bhh_b, dec_bih, dec_bhh,
                                     bias_f, bias_b, bias_d);

    // encoder scan: 64 sequential steps, both directions batched per launch
    for (int t = 0; t < SRCL; ++t) {
        enc_step_gemm<<<dim3(32, 8, 2), 256, 0, stream>>>(
            emb_e, t, h_f, h_b, Wih_f, Whh_f, Wih_b, Whh_b, bias_f, bias_b, gates);
        enc_elem<<<dim3(1024, 2), 256, 0, stream>>>(gates, h_f, c_f, h_b, c_b, es, t);
    }

    // hidden_h = [hf|hb] @ fc_h_W^T + fc_h_b ; hidden_c likewise
    gemm2_kernel<<<dim3(8, 8), 256, 0, stream>>>(
        h_f, HSZ, h_b, HSZ, fc_h_W, 2 * HSZ, fc_h_W + HSZ, 2 * HSZ,
        HSZ, HSZ, fc_h_b, hid_h, HSZ, HSZ, 0);
    gemm2_kernel<<<dim3(8, 8), 256, 0, stream>>>(
        c_f, HSZ, c_b, HSZ, fc_c_W, 2 * HSZ, fc_c_W + HSZ, 2 * HSZ,
        HSZ, HSZ, fc_c_b, hid_c, HSZ, HSZ, 0);

    // attention
    eh_kernel<<<128, 256, 0, stream>>>(hid_h, energy_W, energy_b, ehv);
    energy_kernel<<<8192, 256, 0, stream>>>(es, energy_W + HSZ, ehv, energy);
    softmax_kernel<<<128, 256, 0, stream>>>(energy, attn);
    context_kernel<<<512, 256, 0, stream>>>(attn, es, ctx);

    // D0 = ctx @ dec_Wih[:, :1024]^T + (bih+bhh)  ;  D0 += hidden_h @ dec_Whh^T
    gemm2_kernel<<<dim3(32, 8), 256, 0, stream>>>(
        ctx, 2 * HSZ, nullptr, 0, dec_Wih, 2 * HSZ + ESZ, nullptr, 0,
        2 * HSZ, 0, bias_d, D0, G4, G4, 0);
    gemm2_kernel<<<dim3(32, 8), 256, 0, stream>>>(
        hid_h, HSZ, nullptr, 0, dec_Whh, HSZ, nullptr, 0,
        HSZ, 0, nullptr, D0, G4, G4, 1);

    // decoder fused gates + LSTM pointwise -> h_new (47*512 x 512)
    dec_fused<<<dim3(8, 376), 256, 0, stream>>>(emb_d, dec_Wih, D0, hid_c, h_new);

    // outputs: row 0 zeros, then logits = h_new @ fc_out_W^T + fc_out_b
    zero_kernel<<<134, 256, 0, stream>>>(out, BATCH * ODIM);
    gemm2_kernel<<<dim3(2, 376), 256, 0, stream>>>(
        h_new, HSZ, nullptr, 0, fc_out_W, HSZ, nullptr, 0,
        HSZ, 0, fc_out_b, out + BATCH * ODIM, ODIM, ODIM, 0);
}

// Round 2
// 2747.894 us; speedup vs baseline: 2.2589x; 2.2589x over previous
//
#include <hip/hip_runtime.h>
#include <cstddef>

#define BATCH 512
#define ESZ   256
#define HSZ   512
#define G4    2048      // 4*HS
#define SRCL  64
#define TRGL  48
#define ODIM  67
#define DECM  (47*512)  // 24064 decoder rows

typedef __bf16  bf8v   __attribute__((ext_vector_type(8)));
typedef float   floatx4 __attribute__((ext_vector_type(4)));

__device__ __forceinline__ float sigm(float x) { return 1.0f / (1.0f + expf(-x)); }

// ---------------- embedding gather -> bf16: out[row] = bf16(table[tok[row]]) ----------------
__global__ void embed_bf16(const int* __restrict__ tok, const float* __restrict__ table,
                           __bf16* __restrict__ out, int n_rows) {
    int i = blockIdx.x * 256 + threadIdx.x;   // 8 elements per thread, 32 threads/row
    int row = i >> 5;
    if (row >= n_rows) return;
    int e = (i & 31) << 3;
    const float* src = table + (size_t)tok[row] * ESZ + e;
    float4 a = *(const float4*)src;
    float4 b = *(const float4*)(src + 4);
    bf8v v;
    v[0] = (__bf16)a.x; v[1] = (__bf16)a.y; v[2] = (__bf16)a.z; v[3] = (__bf16)a.w;
    v[4] = (__bf16)b.x; v[5] = (__bf16)b.y; v[6] = (__bf16)b.z; v[7] = (__bf16)b.w;
    *(bf8v*)(out + (size_t)row * ESZ + e) = v;
}

__global__ void zero_kernel(float* __restrict__ p, int n) {
    int i = blockIdx.x * 256 + threadIdx.x;
    if (i < n) p[i] = 0.f;
}

// bias folds: bih+bhh for enc_f, enc_b, dec
__global__ void bias_prep(const float* __restrict__ af, const float* __restrict__ bf,
                          const float* __restrict__ ab, const float* __restrict__ bb,
                          const float* __restrict__ ad, const float* __restrict__ bd,
                          float* __restrict__ of, float* __restrict__ ob, float* __restrict__ od) {
    int i = blockIdx.x * 256 + threadIdx.x;
    if (i < G4) { of[i] = af[i] + bf[i]; ob[i] = ab[i] + bb[i]; od[i] = ad[i] + bd[i]; }
}

// Wcat[n][0:256] = Wih[n][:], Wcat[n][256:768] = Whh[n][:]   (bf16, 2048 x 768)
__global__ void wcat_bf16(const float* __restrict__ Wih, const float* __restrict__ Whh,
                          __bf16* __restrict__ Wc) {
    int i = blockIdx.x * 256 + threadIdx.x;      // 2048*768/8 = 196608 threads
    int n = i / 96;
    int e = (i - n * 96) << 3;                   // 0..760 step 8
    const float* src = (e < ESZ) ? (Wih + (size_t)n * ESZ + e)
                                 : (Whh + (size_t)n * HSZ + (e - ESZ));
    float4 a = *(const float4*)src;
    float4 b = *(const float4*)(src + 4);
    bf8v v;
    v[0] = (__bf16)a.x; v[1] = (__bf16)a.y; v[2] = (__bf16)a.z; v[3] = (__bf16)a.w;
    v[4] = (__bf16)b.x; v[5] = (__bf16)b.y; v[6] = (__bf16)b.z; v[7] = (__bf16)b.w;
    *(bf8v*)(Wc + (size_t)n * 768 + e) = v;
}

// decWe[n][k] = bf16(dec_Wih[n][1024+k]), 2048 x 256
__global__ void decw_bf16(const float* __restrict__ dec_Wih, __bf16* __restrict__ We) {
    int i = blockIdx.x * 256 + threadIdx.x;      // 2048*32 = 65536 threads
    int n = i >> 5;
    int e = (i & 31) << 3;
    const float* src = dec_Wih + (size_t)n * (2 * HSZ + ESZ) + 2 * HSZ + e;
    float4 a = *(const float4*)src;
    float4 b = *(const float4*)(src + 4);
    bf8v v;
    v[0] = (__bf16)a.x; v[1] = (__bf16)a.y; v[2] = (__bf16)a.z; v[3] = (__bf16)a.w;
    v[4] = (__bf16)b.x; v[5] = (__bf16)b.y; v[6] = (__bf16)b.z; v[7] = (__bf16)b.w;
    *(bf8v*)(We + (size_t)n * ESZ + e) = v;
}

// ---------------- encoder step, bf16 MFMA, fused LSTM epilogue ----------------
// gates = [x_t | h_prev] @ Wcat^T + bias ; per wave: 16 m-rows x 32 j-cols x 4 gates.
// grid: (j-tiles=16, m-tiles=8, dir=2), block 256 (4 waves).
__global__ __launch_bounds__(256) void enc_step_mfma(
    const __bf16* __restrict__ embE, const __bf16* __restrict__ hPrev,
    __bf16* __restrict__ hNext, float* __restrict__ c, float* __restrict__ es,
    const __bf16* __restrict__ WcatF, const __bf16* __restrict__ WcatB,
    const float* __restrict__ biasF, const float* __restrict__ biasB, int t)
{
    const int dir = blockIdx.z;
    const int tt = dir ? (SRCL - 1 - t) : t;
    const __bf16* Wc  = dir ? WcatB : WcatF;
    const float*  bias = dir ? biasB : biasF;

    const int tid = threadIdx.x;
    const int w = tid >> 6, lane = tid & 63;
    const int quad = lane >> 4, l15 = lane & 15;
    const int mA = blockIdx.y * 64 + w * 16 + l15;     // A-operand row
    const int j0 = blockIdx.x * 32;

    const __bf16* Ax = embE + ((size_t)(tt * BATCH + mA)) * ESZ + quad * 8;
    const __bf16* Ah = hPrev + ((size_t)(dir * BATCH + mA)) * HSZ + quad * 8;

    const __bf16* Brow[4][2];
#pragma unroll
    for (int g = 0; g < 4; ++g)
#pragma unroll
        for (int ni = 0; ni < 2; ++ni)
            Brow[g][ni] = Wc + ((size_t)(g * HSZ + j0 + ni * 16 + l15)) * 768 + quad * 8;

    floatx4 acc[4][2] = {};

#pragma unroll 4
    for (int kt = 0; kt < 8; ++kt) {                   // x part: k = kt*32
        bf8v a = *(const bf8v*)(Ax + kt * 32);
#pragma unroll
        for (int g = 0; g < 4; ++g)
#pragma unroll
            for (int ni = 0; ni < 2; ++ni) {
                bf8v b = *(const bf8v*)(Brow[g][ni] + kt * 32);
                acc[g][ni] = __builtin_amdgcn_mfma_f32_16x16x32_bf16(a, b, acc[g][ni], 0, 0, 0);
            }
    }
#pragma unroll 4
    for (int kt = 0; kt < 16; ++kt) {                  // h part: k = 256 + kt*32
        bf8v a = *(const bf8v*)(Ah + kt * 32);
#pragma unroll
        for (int g = 0; g < 4; ++g)
#pragma unroll
            for (int ni = 0; ni < 2; ++ni) {
                bf8v b = *(const bf8v*)(Brow[g][ni] + ESZ + kt * 32);
                acc[g][ni] = __builtin_amdgcn_mfma_f32_16x16x32_bf16(a, b, acc[g][ni], 0, 0, 0);
            }
    }

    // epilogue: D row (M) = quad*4 + r, D col (N) = l15
    const int mbase = blockIdx.y * 64 + w * 16 + quad * 4;
#pragma unroll
    for (int ni = 0; ni < 2; ++ni) {
        int j = j0 + ni * 16 + l15;
#pragma unroll
        for (int r = 0; r < 4; ++r) {
            int mr = mbase + r;
            float gi = acc[0][ni][r] + bias[j];
            float gf = acc[1][ni][r] + bias[HSZ + j];
            float gg = acc[2][ni][r] + bias[2 * HSZ + j];
            float go = acc[3][ni][r] + bias[3 * HSZ + j];
            size_t ci = (size_t)(dir * BATCH + mr) * HSZ + j;
            float cn = sigm(gf) * c[ci] + sigm(gi) * tanhf(gg);
            c[ci] = cn;
            float hn = sigm(go) * tanhf(cn);
            hNext[ci] = (__bf16)hn;
            es[((size_t)tt * BATCH + mr) * (2 * HSZ) + dir * HSZ + j] = hn;
        }
    }
}

// ---------------- decoder, bf16 MFMA, fused LSTM epilogue ----------------
// gates[m][n] = emb_d[m] . We[n] + D0[b][n] ; m = t*512+b. grid (16, 376), block 256.
__global__ __launch_bounds__(256) void dec_mfma(
    const __bf16* __restrict__ embD, const __bf16* __restrict__ We,
    const float* __restrict__ D0, const float* __restrict__ hidc,
    float* __restrict__ h_new)
{
    const int tid = threadIdx.x;
    const int w = tid >> 6, lane = tid & 63;
    const int quad = lane >> 4, l15 = lane & 15;
    const int mA = blockIdx.y * 64 + w * 16 + l15;
    const int j0 = blockIdx.x * 32;

    const __bf16* Ar = embD + (size_t)mA * ESZ + quad * 8;
    const __bf16* Brow[4][2];
#pragma unroll
    for (int g = 0; g < 4; ++g)
#pragma unroll
        for (int ni = 0; ni < 2; ++ni)
            Brow[g][ni] = We + ((size_t)(g * HSZ + j0 + ni * 16 + l15)) * ESZ + quad * 8;

    floatx4 acc[4][2] = {};
#pragma unroll 4
    for (int kt = 0; kt < 8; ++kt) {
        bf8v a = *(const bf8v*)(Ar + kt * 32);
#pragma unroll
        for (int g = 0; g < 4; ++g)
#pragma unroll
            for (int ni = 0; ni < 2; ++ni) {
                bf8v b = *(const bf8v*)(Brow[g][ni] + kt * 32);
                acc[g][ni] = __builtin_amdgcn_mfma_f32_16x16x32_bf16(a, b, acc[g][ni], 0, 0, 0);
            }
    }

    const int mbase = blockIdx.y * 64 + w * 16 + quad * 4;
#pragma unroll
    for (int ni = 0; ni < 2; ++ni) {
        int j = j0 + ni * 16 + l15;
#pragma unroll
        for (int r = 0; r < 4; ++r) {
            int mr = mbase + r;
            int b = mr & (BATCH - 1);
            const float* d0 = D0 + (size_t)b * G4;
            float gi = acc[0][ni][r] + d0[j];
            float gf = acc[1][ni][r] + d0[HSZ + j];
            float gg = acc[2][ni][r] + d0[2 * HSZ + j];
            float go = acc[3][ni][r] + d0[3 * HSZ + j];
            float cn = sigm(gf) * hidc[(size_t)b * HSZ + j] + sigm(gi) * tanhf(gg);
            h_new[(size_t)mr * HSZ + j] = sigm(go) * tanhf(cn);
        }
    }
}

// ---------------- generic fp32 GEMM (round-1, verified) ----------------
__device__ __forceinline__ void gemm_core(
    float (*As)[64], float (*Bs)[64],
    const float* __restrict__ A1, int lda1,
    const float* __restrict__ A2, int lda2,
    const float* __restrict__ B1, int ldb1,
    const float* __restrict__ B2, int ldb2,
    int K1, int K2,
    const float* __restrict__ bias,
    float* __restrict__ C, int ldc, int N, int add_c,
    int m0, int n0)
{
    const int tid = threadIdx.x;
    const int tm = (tid >> 4) << 2;
    const int tn = (tid & 15) << 2;
    const int lr = tid >> 2;
    const int lk = (tid & 3) << 2;
    float acc[4][4] = {};
    const int K = K1 + K2;
    for (int kt = 0; kt < K; kt += 16) {
        const float* Ap; const float* Bp; int kc, lda, ldb;
        if (kt < K1) { Ap = A1; Bp = B1; kc = kt;      lda = lda1; ldb = ldb1; }
        else         { Ap = A2; Bp = B2; kc = kt - K1; lda = lda2; ldb = ldb2; }
        float4 va = *(const float4*)(Ap + (size_t)(m0 + lr) * lda + kc + lk);
        As[lk + 0][lr] = va.x; As[lk + 1][lr] = va.y;
        As[lk + 2][lr] = va.z; As[lk + 3][lr] = va.w;
        int gn = n0 + lr;
        float4 vb = make_float4(0.f, 0.f, 0.f, 0.f);
        if (gn < N) vb = *(const float4*)(Bp + (size_t)gn * ldb + kc + lk);
        Bs[lk + 0][lr] = vb.x; Bs[lk + 1][lr] = vb.y;
        Bs[lk + 2][lr] = vb.z; Bs[lk + 3][lr] = vb.w;
        __syncthreads();
#pragma unroll
        for (int kk = 0; kk < 16; ++kk) {
            float a0 = As[kk][tm + 0], a1 = As[kk][tm + 1];
            float a2 = As[kk][tm + 2], a3 = As[kk][tm + 3];
            float w0 = Bs[kk][tn + 0], w1 = Bs[kk][tn + 1];
            float w2 = Bs[kk][tn + 2], w3 = Bs[kk][tn + 3];
            acc[0][0] += a0 * w0; acc[0][1] += a0 * w1; acc[0][2] += a0 * w2; acc[0][3] += a0 * w3;
            acc[1][0] += a1 * w0; acc[1][1] += a1 * w1; acc[1][2] += a1 * w2; acc[1][3] += a1 * w3;
            acc[2][0] += a2 * w0; acc[2][1] += a2 * w1; acc[2][2] += a2 * w2; acc[2][3] += a2 * w3;
            acc[3][0] += a3 * w0; acc[3][1] += a3 * w1; acc[3][2] += a3 * w2; acc[3][3] += a3 * w3;
        }
        __syncthreads();
    }
#pragma unroll
    for (int mi = 0; mi < 4; ++mi) {
        int m = m0 + tm + mi;
#pragma unroll
        for (int jj = 0; jj < 4; ++jj) {
            int n = n0 + tn + jj;
            if (n < N) {
                float v = acc[mi][jj];
                if (bias) v += bias[n];
                size_t ci = (size_t)m * ldc + n;
                if (add_c) v += C[ci];
                C[ci] = v;
            }
        }
    }
}

__global__ __launch_bounds__(256) void gemm2_kernel(
    const float* A1, int lda1, const float* A2, int lda2,
    const float* B1, int ldb1, const float* B2, int ldb2,
    int K1, int K2, const float* bias, float* C, int ldc, int N, int add_c)
{
    __shared__ float As[16][64];
    __shared__ float Bs[16][64];
    gemm_core(As, Bs, A1, lda1, A2, lda2, B1, ldb1, B2, ldb2, K1, K2,
              bias, C, ldc, N, add_c, blockIdx.y * 64, blockIdx.x * 64);
}

// ---------------- attention (fp32, round-1 verified) ----------------
__global__ void eh_kernel(const float* __restrict__ hid_h, const float* __restrict__ eW,
                          const float* __restrict__ eb, float* __restrict__ eh) {
    int w = blockIdx.x * 4 + (threadIdx.x >> 6);
    int lane = threadIdx.x & 63;
    if (w >= BATCH) return;
    float s = 0.f;
    for (int k = lane; k < HSZ; k += 64) s += hid_h[(size_t)w * HSZ + k] * eW[k];
    for (int off = 32; off; off >>= 1) s += __shfl_down(s, off);
    if (lane == 0) eh[w] = s + eb[0];
}

__global__ void energy_kernel(const float* __restrict__ es, const float* __restrict__ eW2,
                              const float* __restrict__ eh, float* __restrict__ energy) {
    int w = blockIdx.x * 4 + (threadIdx.x >> 6);
    int lane = threadIdx.x & 63;
    int s = w >> 9, b = w & 511;
    const float* row = es + ((size_t)s * BATCH + b) * (2 * HSZ);
    float v = 0.f;
    for (int k = lane; k < 2 * HSZ; k += 64) v += row[k] * eW2[k];
    for (int off = 32; off; off >>= 1) v += __shfl_down(v, off);
    if (lane == 0) energy[(size_t)s * BATCH + b] = fmaxf(v + eh[b], 0.f);
}

__global__ void softmax_kernel(const float* __restrict__ energy, float* __restrict__ attn) {
    int b = blockIdx.x * 4 + (threadIdx.x >> 6);
    int lane = threadIdx.x & 63;
    if (b >= BATCH) return;
    float v = energy[(size_t)lane * BATCH + b];
    float m = v;
    for (int off = 32; off; off >>= 1) m = fmaxf(m, __shfl_xor(m, off));
    float e = expf(v - m);
    float sum = e;
    for (int off = 32; off; off >>= 1) sum += __shfl_xor(sum, off);
    attn[(size_t)lane * BATCH + b] = e / sum;
}

__global__ void context_kernel(const float* __restrict__ attn, const float* __restrict__ es,
                               float* __restrict__ ctx) {
    int b = blockIdx.x;
    int j = threadIdx.x * 4;
    float4 acc = make_float4(0.f, 0.f, 0.f, 0.f);
    for (int s = 0; s < SRCL; ++s) {
        float a = attn[(size_t)s * BATCH + b];
        float4 v = *(const float4*)(es + ((size_t)s * BATCH + b) * (2 * HSZ) + j);
        acc.x += a * v.x; acc.y += a * v.y; acc.z += a * v.z; acc.w += a * v.w;
    }
    *(float4*)(ctx + (size_t)b * (2 * HSZ) + j) = acc;
}

// ---------------- launch ----------------
extern "C" void kernel_launch(void* const* d_in, const int* in_sizes, int n_in,
                              void* d_out, int out_size, void* d_ws, size_t ws_size,
                              hipStream_t stream) {
    const int*   src      = (const int*)d_in[0];
    const int*   trg      = (const int*)d_in[1];
    const float* enc_emb  = (const float*)d_in[2];
    const float* Wih_f    = (const float*)d_in[3];
    const float* Whh_f    = (const float*)d_in[4];
    const float* bih_f    = (const float*)d_in[5];
    const float* bhh_f    = (const float*)d_in[6];
    const float* Wih_b    = (const float*)d_in[7];
    const float* Whh_b    = (const float*)d_in[8];
    const float* bih_b    = (const float*)d_in[9];
    const float* bhh_b    = (const float*)d_in[10];
    const float* fc_h_W   = (const float*)d_in[11];
    const float* fc_h_b   = (const float*)d_in[12];
    const float* fc_c_W   = (const float*)d_in[13];
    const float* fc_c_b   = (const float*)d_in[14];
    const float* dec_emb  = (const float*)d_in[15];
    const float* dec_Wih  = (const float*)d_in[16];
    const float* dec_Whh  = (const float*)d_in[17];
    const float* dec_bih  = (const float*)d_in[18];
    const float* dec_bhh  = (const float*)d_in[19];
    const float* energy_W = (const float*)d_in[20];
    const float* energy_b = (const float*)d_in[21];
    const float* fc_out_W = (const float*)d_in[22];
    const float* fc_out_b = (const float*)d_in[23];
    float* out = (float*)d_out;

    // workspace layout (units of float, all 16B-aligned)
    float* ws    = (float*)d_ws;
    __bf16* embE = (__bf16*)ws;                       // 64*512*256 bf16 = 4194304 f
    __bf16* embD = (__bf16*)(ws + 4194304);           // 47*512*256 bf16 = 3080192 f
    float* es    = ws + 4194304 + 3080192;            // 33554432 f
    float* base  = es + 33554432;
    __bf16* h0   = (__bf16*)base;                     // 2*512*512 bf16 = 262144 f
    __bf16* h1   = (__bf16*)(base + 262144);          // 262144 f
    float* cbuf  = base + 524288;                     // 2*512*512 = 524288 f
    __bf16* WcF  = (__bf16*)(base + 1048576);         // 2048*768 bf16 = 786432 f
    __bf16* WcB  = (__bf16*)(base + 1048576 + 786432);
    __bf16* decWe= (__bf16*)(base + 1048576 + 2*786432);  // 2048*256 bf16 = 262144 f
    float* hid_h = base + 1048576 + 2*786432 + 262144;
    float* hid_c = hid_h + 262144;
    float* ehv   = hid_c + 262144;                    // 512
    float* energy= ehv + 512;                         // 32768
    float* attn  = energy + 32768;                    // 32768
    float* ctx   = attn + 32768;                      // 524288
    float* D0    = ctx + 524288;                      // 1048576
    float* bias_f= D0 + 1048576;                      // 2048
    float* bias_b= bias_f + 2048;
    float* bias_d= bias_b + 2048;
    float* h_new = bias_d + 2048;                     // 24064*512 = 12320768 f
    // total ~58.3M floats ~233 MB

    // prep: embeddings (bf16), weight conversions, bias folds, zero h0/h1/c
    embed_bf16<<<4096, 256, 0, stream>>>(src, enc_emb, embE, SRCL * BATCH);
    embed_bf16<<<3008, 256, 0, stream>>>(trg, dec_emb, embD, (TRGL - 1) * BATCH);
    zero_kernel<<<4096, 256, 0, stream>>>(base, 1048576);   // h0,h1,c contiguous
    bias_prep<<<8, 256, 0, stream>>>(bih_f, bhh_f, bih_b, bhh_b, dec_bih, dec_bhh,
                                     bias_f, bias_b, bias_d);
    wcat_bf16<<<768, 256, 0, stream>>>(Wih_f, Whh_f, WcF);
    wcat_bf16<<<768, 256, 0, stream>>>(Wih_b, Whh_b, WcB);
    decw_bf16<<<256, 256, 0, stream>>>(dec_Wih, decWe);

    // encoder scan: 64 sequential fused MFMA steps, h ping-pong
    for (int t = 0; t < SRCL; ++t) {
        const __bf16* hp = (t & 1) ? h1 : h0;
        __bf16*       hn = (t & 1) ? h0 : h1;
        enc_step_mfma<<<dim3(16, 8, 2), 256, 0, stream>>>(
            embE, hp, hn, cbuf, es, WcF, WcB, bias_f, bias_b, t);
    }

    // hidden_h = [hf|hb] @ fc_h_W^T + b  (hf = es[63][:, :512], hb = es[0][:, 512:])
    gemm2_kernel<<<dim3(8, 8), 256, 0, stream>>>(
        es + (size_t)63 * BATCH * 2 * HSZ, 2 * HSZ, es + HSZ, 2 * HSZ,
        fc_h_W, 2 * HSZ, fc_h_W + HSZ, 2 * HSZ,
        HSZ, HSZ, fc_h_b, hid_h, HSZ, HSZ, 0);
    gemm2_kernel<<<dim3(8, 8), 256, 0, stream>>>(
        cbuf, HSZ, cbuf + (size_t)BATCH * HSZ, HSZ,
        fc_c_W, 2 * HSZ, fc_c_W + HSZ, 2 * HSZ,
        HSZ, HSZ, fc_c_b, hid_c, HSZ, HSZ, 0);

    // attention (fp32)
    eh_kernel<<<128, 256, 0, stream>>>(hid_h, energy_W, energy_b, ehv);
    energy_kernel<<<8192, 256, 0, stream>>>(es, energy_W + HSZ, ehv, energy);
    softmax_kernel<<<128, 256, 0, stream>>>(energy, attn);
    context_kernel<<<512, 256, 0, stream>>>(attn, es, ctx);

    // D0 = ctx @ dec_Wih[:, :1024]^T + (bih+bhh) ; D0 += hidden_h @ dec_Whh^T (fp32)
    gemm2_kernel<<<dim3(32, 8), 256, 0, stream>>>(
        ctx, 2 * HSZ, nullptr, 0, dec_Wih, 2 * HSZ + ESZ, nullptr, 0,
        2 * HSZ, 0, bias_d, D0, G4, G4, 0);
    gemm2_kernel<<<dim3(32, 8), 256, 0, stream>>>(
        hid_h, HSZ, nullptr, 0, dec_Whh, HSZ, nullptr, 0,
        HSZ, 0, nullptr, D0, G4, G4, 1);

    // decoder: bf16 MFMA fused gates + pointwise -> h_new
    dec_mfma<<<dim3(16, 376), 256, 0, stream>>>(embD, decWe, D0, hid_c, h_new);

    // outputs: row 0 zeros, logits = h_new @ fc_out_W^T + b (fp32)
    zero_kernel<<<134, 256, 0, stream>>>(out, BATCH * ODIM);
    gemm2_kernel<<<dim3(2, 376), 256, 0, stream>>>(
        h_new, HSZ, nullptr, 0, fc_out_W, HSZ, nullptr, 0,
        HSZ, 0, fc_out_b, out + BATCH * ODIM, ODIM, ODIM, 0);
}

// Round 3
// 1315.089 us; speedup vs baseline: 4.7200x; 2.0895x over previous
//
#include <hip/hip_runtime.h>
#include <cstddef>

#define BATCH 512
#define ESZ   256
#define HSZ   512
#define G4    2048      // 4*HS
#define SRCL  64
#define TRGL  48
#define ODIM  67

typedef __bf16  bf8v    __attribute__((ext_vector_type(8)));
typedef float   floatx4 __attribute__((ext_vector_type(4)));

// fast transcendentals: v_exp_f32 + v_rcp_f32
__device__ __forceinline__ float frcp(float x) { return __builtin_amdgcn_rcpf(x); }
__device__ __forceinline__ float fsig(float x) { return frcp(1.0f + __expf(-x)); }
__device__ __forceinline__ float ftanh(float x) { return 1.0f - 2.0f * frcp(1.0f + __expf(2.0f * x)); }

// ---------------- small prep kernels ----------------
__global__ void embed_bf16(const int* __restrict__ tok, const float* __restrict__ table,
                           __bf16* __restrict__ out, int n_rows) {
    int i = blockIdx.x * 256 + threadIdx.x;   // 8 elems/thread, 32 thr/row
    int row = i >> 5;
    if (row >= n_rows) return;
    int e = (i & 31) << 3;
    const float* src = table + (size_t)tok[row] * ESZ + e;
    float4 a = *(const float4*)src;
    float4 b = *(const float4*)(src + 4);
    bf8v v;
    v[0] = (__bf16)a.x; v[1] = (__bf16)a.y; v[2] = (__bf16)a.z; v[3] = (__bf16)a.w;
    v[4] = (__bf16)b.x; v[5] = (__bf16)b.y; v[6] = (__bf16)b.z; v[7] = (__bf16)b.w;
    *(bf8v*)(out + (size_t)row * ESZ + e) = v;
}

__global__ void zero_kernel(float* __restrict__ p, int n) {
    int i = blockIdx.x * 256 + threadIdx.x;
    if (i < n) p[i] = 0.f;
}

__global__ void bias_prep(const float* __restrict__ af, const float* __restrict__ bf,
                          const float* __restrict__ ab, const float* __restrict__ bb,
                          const float* __restrict__ ad, const float* __restrict__ bd,
                          float* __restrict__ of, float* __restrict__ ob, float* __restrict__ od) {
    int i = blockIdx.x * 256 + threadIdx.x;
    if (i < G4) { of[i] = af[i] + bf[i]; ob[i] = ab[i] + bb[i]; od[i] = ad[i] + bd[i]; }
}

__device__ __forceinline__ bf8v cvt8(const float* __restrict__ s) {
    float4 a = *(const float4*)s;
    float4 b = *(const float4*)(s + 4);
    bf8v v;
    v[0] = (__bf16)a.x; v[1] = (__bf16)a.y; v[2] = (__bf16)a.z; v[3] = (__bf16)a.w;
    v[4] = (__bf16)b.x; v[5] = (__bf16)b.y; v[6] = (__bf16)b.z; v[7] = (__bf16)b.w;
    return v;
}

// Wcat[n][0:256]=Wih[n], [256:768]=Whh[n]  (2048 x 768 bf16)
__global__ void wcat_bf16(const float* __restrict__ Wih, const float* __restrict__ Whh,
                          __bf16* __restrict__ Wc) {
    int i = blockIdx.x * 256 + threadIdx.x;      // 196608 threads
    int n = i / 96;
    int e = (i - n * 96) << 3;
    const float* src = (e < ESZ) ? (Wih + (size_t)n * ESZ + e)
                                 : (Whh + (size_t)n * HSZ + (e - ESZ));
    *(bf8v*)(Wc + (size_t)n * 768 + e) = cvt8(src);
}

// decWe[n][k] = dec_Wih[n][1024+k]  (2048 x 256 bf16)
__global__ void decw_bf16(const float* __restrict__ dec_Wih, __bf16* __restrict__ We) {
    int i = blockIdx.x * 256 + threadIdx.x;      // 65536 threads
    int n = i >> 5;
    int e = (i & 31) << 3;
    *(bf8v*)(We + (size_t)n * ESZ + e) =
        cvt8(dec_Wih + (size_t)n * (2 * HSZ + ESZ) + 2 * HSZ + e);
}

// WdC[n][0:1024]=dec_Wih[n][0:1024], [1024:1536]=dec_Whh[n]  (2048 x 1536 bf16)
__global__ void wdcat_bf16(const float* __restrict__ dec_Wih, const float* __restrict__ dec_Whh,
                           __bf16* __restrict__ Wd) {
    int i = blockIdx.x * 256 + threadIdx.x;      // 393216 threads
    int n = i / 192;
    int e = (i - n * 192) << 3;
    const float* src = (e < 1024) ? (dec_Wih + (size_t)n * 1280 + e)
                                  : (dec_Whh + (size_t)n * HSZ + (e - 1024));
    *(bf8v*)(Wd + (size_t)n * 1536 + e) = cvt8(src);
}

// generic contiguous f32 -> bf16
__global__ void conv_f2b(const float* __restrict__ src, __bf16* __restrict__ dst, int n8) {
    int i = blockIdx.x * 256 + threadIdx.x;
    if (i < n8) *(bf8v*)(dst + (size_t)i * 8) = cvt8(src + (size_t)i * 8);
}

// fc_out_W padded to 128 rows x 512 bf16
__global__ void fo_pad(const float* __restrict__ W, __bf16* __restrict__ dst) {
    int i = blockIdx.x * 256 + threadIdx.x;      // 8192 threads
    int r = i >> 6, e = (i & 63) << 3;
    bf8v v;
    if (r < ODIM) v = cvt8(W + (size_t)r * HSZ + e);
    else { for (int k = 0; k < 8; ++k) v[k] = (__bf16)0.f; }
    *(bf8v*)(dst + (size_t)r * HSZ + e) = v;
}

// hfb[r] = [es[63][r][0:512] | es[0][r][512:1024]]  (bf16 copy)
__global__ void cat_hfb(const __bf16* __restrict__ es, __bf16* __restrict__ dst) {
    int i = blockIdx.x * 256 + threadIdx.x;      // 65536 threads
    int r = i >> 7, e = (i & 127) << 3;
    const __bf16* s = (e < HSZ) ? (es + ((size_t)(63 * BATCH + r)) * 1024 + e)
                                : (es + (size_t)r * 1024 + e);
    *(bf8v*)(dst + (size_t)r * 1024 + e) = *(const bf8v*)s;
}

// cfb[r] = bf16([cf[r] | cb[r]]) from cbuf fp32 [2][512][512]
__global__ void cat_cfb(const float* __restrict__ cbuf, __bf16* __restrict__ dst) {
    int i = blockIdx.x * 256 + threadIdx.x;      // 65536 threads
    int r = i >> 7, e = (i & 127) << 3;
    const float* s = (e < HSZ) ? (cbuf + (size_t)r * HSZ + e)
                               : (cbuf + (size_t)BATCH * HSZ + (size_t)r * HSZ + (e - HSZ));
    *(bf8v*)(dst + (size_t)r * 1024 + e) = cvt8(s);
}

// ctxh[r] = bf16([ctx[r] (1024) | hid_h[r] (512)])
__global__ void cat_ctxh(const float* __restrict__ ctx, const float* __restrict__ hid_h,
                         __bf16* __restrict__ dst) {
    int i = blockIdx.x * 256 + threadIdx.x;      // 98304 threads
    int r = i / 192;
    int e = (i - r * 192) << 3;
    const float* s = (e < 1024) ? (ctx + (size_t)r * 1024 + e)
                                : (hid_h + (size_t)r * HSZ + (e - 1024));
    *(bf8v*)(dst + (size_t)r * 1536 + e) = cvt8(s);
}

// ---------------- encoder step v3: LDS-tiled MFMA + fused LSTM ----------------
// gates = [x_t | h_prev] @ Wcat^T + bias. grid (32 j-tiles, 8 m-tiles, 2 dirs), 256 thr.
// Block: 64 m-rows x 64 gate-cols (4 gates x 16 j). Wave (2x2 split): 32m x 32gc.
// LDS: A/B panels 64 x 128k bf16, row stride 136 bf16 (+16B pad -> uniform bank groups).
__global__ __launch_bounds__(256) void enc_step_v3(
    const __bf16* __restrict__ embE, const __bf16* __restrict__ hPrev,
    __bf16* __restrict__ hNext, float* __restrict__ cbuf, __bf16* __restrict__ es,
    const __bf16* __restrict__ WcF, const __bf16* __restrict__ WcB,
    const float* __restrict__ biasF, const float* __restrict__ biasB, int t)
{
    __shared__ __bf16 As[64 * 136];
    __shared__ __bf16 Bs[64 * 136];
    __shared__ float  gbuf[64 * 64];

    const int dir = blockIdx.z;
    const int tt  = dir ? (SRCL - 1 - t) : t;
    const __bf16* Wc   = dir ? WcB : WcF;
    const float*  bias = dir ? biasB : biasF;
    const int j0 = blockIdx.x * 16;
    const int m0 = blockIdx.y * 64;

    const int tid = threadIdx.x;
    const int w = tid >> 6, lane = tid & 63;
    const int quad = lane >> 4, l15 = lane & 15;
    const int mh = (w & 1) * 32, gh = (w >> 1) * 32;

    floatx4 acc[2][2] = {};

    for (int p = 0; p < 6; ++p) {
        __syncthreads();
        // stage A (x for p<2, h for p>=2) and B panel, coalesced, padded stride
#pragma unroll
        for (int i = 0; i < 4; ++i) {
            int idx = tid + i * 256;
            int r = idx >> 4, kq = idx & 15;
            const __bf16* srcA;
            if (p < 2) srcA = embE + ((size_t)(tt * BATCH + m0 + r)) * ESZ + p * 128 + kq * 8;
            else       srcA = hPrev + ((size_t)(dir * BATCH + m0 + r)) * HSZ + (p - 2) * 128 + kq * 8;
            *(bf8v*)(As + r * 136 + kq * 8) = *(const bf8v*)srcA;
            int wrow = (r >> 4) * HSZ + j0 + (r & 15);
            *(bf8v*)(Bs + r * 136 + kq * 8) =
                *(const bf8v*)(Wc + (size_t)wrow * 768 + p * 128 + kq * 8);
        }
        __syncthreads();
#pragma unroll
        for (int ks = 0; ks < 4; ++ks) {
            int ko = (ks * 4 + quad) * 8;
            bf8v a0 = *(const bf8v*)(As + (mh + l15) * 136 + ko);
            bf8v a1 = *(const bf8v*)(As + (mh + 16 + l15) * 136 + ko);
            bf8v b0 = *(const bf8v*)(Bs + (gh + l15) * 136 + ko);
            bf8v b1 = *(const bf8v*)(Bs + (gh + 16 + l15) * 136 + ko);
            acc[0][0] = __builtin_amdgcn_mfma_f32_16x16x32_bf16(a0, b0, acc[0][0], 0, 0, 0);
            acc[0][1] = __builtin_amdgcn_mfma_f32_16x16x32_bf16(a0, b1, acc[0][1], 0, 0, 0);
            acc[1][0] = __builtin_amdgcn_mfma_f32_16x16x32_bf16(a1, b0, acc[1][0], 0, 0, 0);
            acc[1][1] = __builtin_amdgcn_mfma_f32_16x16x32_bf16(a1, b1, acc[1][1], 0, 0, 0);
        }
    }

    // exchange gates through LDS: gbuf[m][c], c = gate*16 + jj
#pragma unroll
    for (int ms = 0; ms < 2; ++ms)
#pragma unroll
        for (int cs = 0; cs < 2; ++cs)
#pragma unroll
            for (int r = 0; r < 4; ++r)
                gbuf[(mh + ms * 16 + quad * 4 + r) * 64 + gh + cs * 16 + l15] = acc[ms][cs][r];
    __syncthreads();

    // fused LSTM pointwise: 1024 elems (64m x 16j), 4 per thread
#pragma unroll
    for (int i = 0; i < 4; ++i) {
        int e = tid + i * 256;
        int m = e >> 4, jj = e & 15;
        float gi = gbuf[m * 64 + jj]      + bias[j0 + jj];
        float gf = gbuf[m * 64 + 16 + jj] + bias[HSZ + j0 + jj];
        float gg = gbuf[m * 64 + 32 + jj] + bias[2 * HSZ + j0 + jj];
        float go = gbuf[m * 64 + 48 + jj] + bias[3 * HSZ + j0 + jj];
        size_t ci = (size_t)(dir * BATCH + m0 + m) * HSZ + j0 + jj;
        float cn = fsig(gf) * cbuf[ci] + fsig(gi) * ftanh(gg);
        cbuf[ci] = cn;
        float hn = fsig(go) * ftanh(cn);
        hNext[ci] = (__bf16)hn;
        es[((size_t)(tt * BATCH + m0 + m)) * (2 * HSZ) + dir * HSZ + j0 + jj] = (__bf16)hn;
    }
}

// ---------------- generic bf16 MFMA GEMM: C = A @ B^T + bias (fp32 out) ----------------
// A: M x K bf16 row-major, B: (>=N-padded) x K bf16 row-major. M % 64 == 0, K % 32 == 0.
// grid (N-tiles of 64, M/64), block 256. Wave: 16m x 64n.
__global__ __launch_bounds__(256) void gmm_bf16(
    const __bf16* __restrict__ A, const __bf16* __restrict__ B, int K,
    const float* __restrict__ bias, float* __restrict__ C, int ldc, int N)
{
    const int tid = threadIdx.x;
    const int w = tid >> 6, lane = tid & 63;
    const int quad = lane >> 4, l15 = lane & 15;
    const int n0 = blockIdx.x * 64;
    const int mA = blockIdx.y * 64 + w * 16 + l15;

    const __bf16* Ar = A + (size_t)mA * K + quad * 8;
    const __bf16* Br[4];
#pragma unroll
    for (int ns = 0; ns < 4; ++ns)
        Br[ns] = B + (size_t)(n0 + ns * 16 + l15) * K + quad * 8;

    floatx4 acc[4] = {};
    const int KT = K >> 5;
#pragma unroll 4
    for (int kt = 0; kt < KT; ++kt) {
        bf8v a = *(const bf8v*)(Ar + kt * 32);
#pragma unroll
        for (int ns = 0; ns < 4; ++ns) {
            bf8v b = *(const bf8v*)(Br[ns] + kt * 32);
            acc[ns] = __builtin_amdgcn_mfma_f32_16x16x32_bf16(a, b, acc[ns], 0, 0, 0);
        }
    }
    const int mb = blockIdx.y * 64 + w * 16 + quad * 4;
#pragma unroll
    for (int ns = 0; ns < 4; ++ns) {
        int n = n0 + ns * 16 + l15;
        if (n < N) {
#pragma unroll
            for (int r = 0; r < 4; ++r)
                C[(size_t)(mb + r) * ldc + n] = acc[ns][r] + bias[n];
        }
    }
}

// ---------------- decoder: bf16 MFMA fused gates + LSTM pointwise ----------------
__global__ __launch_bounds__(256) void dec_mfma(
    const __bf16* __restrict__ embD, const __bf16* __restrict__ We,
    const float* __restrict__ D0, const float* __restrict__ hidc,
    __bf16* __restrict__ h_new)
{
    const int tid = threadIdx.x;
    const int w = tid >> 6, lane = tid & 63;
    const int quad = lane >> 4, l15 = lane & 15;
    const int mA = blockIdx.y * 64 + w * 16 + l15;
    const int j0 = blockIdx.x * 32;

    const __bf16* Ar = embD + (size_t)mA * ESZ + quad * 8;
    const __bf16* Brow[4][2];
#pragma unroll
    for (int g = 0; g < 4; ++g)
#pragma unroll
        for (int ni = 0; ni < 2; ++ni)
            Brow[g][ni] = We + ((size_t)(g * HSZ + j0 + ni * 16 + l15)) * ESZ + quad * 8;

    floatx4 acc[4][2] = {};
#pragma unroll 4
    for (int kt = 0; kt < 8; ++kt) {
        bf8v a = *(const bf8v*)(Ar + kt * 32);
#pragma unroll
        for (int g = 0; g < 4; ++g)
#pragma unroll
            for (int ni = 0; ni < 2; ++ni) {
                bf8v b = *(const bf8v*)(Brow[g][ni] + kt * 32);
                acc[g][ni] = __builtin_amdgcn_mfma_f32_16x16x32_bf16(a, b, acc[g][ni], 0, 0, 0);
            }
    }

    const int mbase = blockIdx.y * 64 + w * 16 + quad * 4;
#pragma unroll
    for (int ni = 0; ni < 2; ++ni) {
        int j = j0 + ni * 16 + l15;
#pragma unroll
        for (int r = 0; r < 4; ++r) {
            int mr = mbase + r;
            int b = mr & (BATCH - 1);
            const float* d0 = D0 + (size_t)b * G4;
            float gi = acc[0][ni][r] + d0[j];
            float gf = acc[1][ni][r] + d0[HSZ + j];
            float gg = acc[2][ni][r] + d0[2 * HSZ + j];
            float go = acc[3][ni][r] + d0[3 * HSZ + j];
            float cn = fsig(gf) * hidc[(size_t)b * HSZ + j] + fsig(gi) * ftanh(gg);
            h_new[(size_t)mr * HSZ + j] = (__bf16)(fsig(go) * ftanh(cn));
        }
    }
}

// ---------------- attention ----------------
__global__ void eh_kernel(const float* __restrict__ hid_h, const float* __restrict__ eW,
                          const float* __restrict__ eb, float* __restrict__ eh) {
    int w = blockIdx.x * 4 + (threadIdx.x >> 6);
    int lane = threadIdx.x & 63;
    if (w >= BATCH) return;
    float s = 0.f;
    for (int k = lane; k < HSZ; k += 64) s += hid_h[(size_t)w * HSZ + k] * eW[k];
    for (int off = 32; off; off >>= 1) s += __shfl_down(s, off);
    if (lane == 0) eh[w] = s + eb[0];
}

__global__ void energy_kernel(const __bf16* __restrict__ es, const float* __restrict__ eW2,
                              const float* __restrict__ eh, float* __restrict__ energy) {
    int w = blockIdx.x * 4 + (threadIdx.x >> 6);
    int lane = threadIdx.x & 63;
    int s = w >> 9, b = w & 511;
    const __bf16* row = es + ((size_t)s * BATCH + b) * (2 * HSZ);
    float v = 0.f;
    for (int k = lane; k < 2 * HSZ; k += 64) v += (float)row[k] * eW2[k];
    for (int off = 32; off; off >>= 1) v += __shfl_down(v, off);
    if (lane == 0) energy[(size_t)s * BATCH + b] = fmaxf(v + eh[b], 0.f);
}

__global__ void softmax_kernel(const float* __restrict__ energy, float* __restrict__ attn) {
    int b = blockIdx.x * 4 + (threadIdx.x >> 6);
    int lane = threadIdx.x & 63;
    if (b >= BATCH) return;
    float v = energy[(size_t)lane * BATCH + b];
    float m = v;
    for (int off = 32; off; off >>= 1) m = fmaxf(m, __shfl_xor(m, off));
    float e = __expf(v - m);
    float sum = e;
    for (int off = 32; off; off >>= 1) sum += __shfl_xor(sum, off);
    attn[(size_t)lane * BATCH + b] = e / sum;
}

__global__ void context_kernel(const float* __restrict__ attn, const __bf16* __restrict__ es,
                               float* __restrict__ ctx) {
    int b = blockIdx.x;
    int j = threadIdx.x * 4;
    float a0 = 0.f, a1 = 0.f, a2 = 0.f, a3 = 0.f;
    for (int s = 0; s < SRCL; ++s) {
        float a = attn[(size_t)s * BATCH + b];
        const __bf16* r = es + ((size_t)s * BATCH + b) * (2 * HSZ) + j;
        a0 += a * (float)r[0]; a1 += a * (float)r[1];
        a2 += a * (float)r[2]; a3 += a * (float)r[3];
    }
    float4 o = make_float4(a0, a1, a2, a3);
    *(float4*)(ctx + (size_t)b * (2 * HSZ) + j) = o;
}

// ---------------- launch ----------------
extern "C" void kernel_launch(void* const* d_in, const int* in_sizes, int n_in,
                              void* d_out, int out_size, void* d_ws, size_t ws_size,
                              hipStream_t stream) {
    const int*   src      = (const int*)d_in[0];
    const int*   trg      = (const int*)d_in[1];
    const float* enc_emb  = (const float*)d_in[2];
    const float* Wih_f    = (const float*)d_in[3];
    const float* Whh_f    = (const float*)d_in[4];
    const float* bih_f    = (const float*)d_in[5];
    const float* bhh_f    = (const float*)d_in[6];
    const float* Wih_b    = (const float*)d_in[7];
    const float* Whh_b    = (const float*)d_in[8];
    const float* bih_b    = (const float*)d_in[9];
    const float* bhh_b    = (const float*)d_in[10];
    const float* fc_h_W   = (const float*)d_in[11];
    const float* fc_h_b   = (const float*)d_in[12];
    const float* fc_c_W   = (const float*)d_in[13];
    const float* fc_c_b   = (const float*)d_in[14];
    const float* dec_emb  = (const float*)d_in[15];
    const float* dec_Wih  = (const float*)d_in[16];
    const float* dec_Whh  = (const float*)d_in[17];
    const float* dec_bih  = (const float*)d_in[18];
    const float* dec_bhh  = (const float*)d_in[19];
    const float* energy_W = (const float*)d_in[20];
    const float* energy_b = (const float*)d_in[21];
    const float* fc_out_W = (const float*)d_in[22];
    const float* fc_out_b = (const float*)d_in[23];
    float* out = (float*)d_out;

    // workspace layout (float units, all 16B aligned)
    float* ws = (float*)d_ws;
    size_t o = 0;
    __bf16* embE = (__bf16*)(ws + o); o += 4194304;   // 64*512*256 bf16
    __bf16* embD = (__bf16*)(ws + o); o += 3080192;   // 47*512*256 bf16
    __bf16* es   = (__bf16*)(ws + o); o += 16777216;  // 64*512*1024 bf16
    float* zbase = ws + o;                            // h0,h1,cbuf contiguous for zeroing
    __bf16* h0   = (__bf16*)(ws + o); o += 262144;    // 2*512*512 bf16
    __bf16* h1   = (__bf16*)(ws + o); o += 262144;
    float*  cbuf = ws + o;            o += 524288;    // 2*512*512 f32
    __bf16* WcF  = (__bf16*)(ws + o); o += 786432;    // 2048*768 bf16
    __bf16* WcB  = (__bf16*)(ws + o); o += 786432;
    __bf16* decWe= (__bf16*)(ws + o); o += 262144;    // 2048*256 bf16
    __bf16* WdC  = (__bf16*)(ws + o); o += 1572864;   // 2048*1536 bf16
    __bf16* fcWh = (__bf16*)(ws + o); o += 262144;    // 512*1024 bf16
    __bf16* fcWc = (__bf16*)(ws + o); o += 262144;
    __bf16* foWb = (__bf16*)(ws + o); o += 32768;     // 128*512 bf16
    __bf16* hfb  = (__bf16*)(ws + o); o += 262144;    // 512*1024 bf16
    __bf16* cfb  = (__bf16*)(ws + o); o += 262144;
    __bf16* ctxh = (__bf16*)(ws + o); o += 393216;    // 512*1536 bf16
    float* hid_h = ws + o;            o += 262144;
    float* hid_c = ws + o;            o += 262144;
    float* ehv   = ws + o;            o += 512;
    float* energy= ws + o;            o += 32768;
    float* attn  = ws + o;            o += 32768;
    float* ctx   = ws + o;            o += 524288;
    float* D0    = ws + o;            o += 1048576;
    float* bias_f= ws + o;            o += 2048;
    float* bias_b= ws + o;            o += 2048;
    float* bias_d= ws + o;            o += 2048;
    __bf16* h_new= (__bf16*)(ws + o); o += 6160384;   // 24064*512 bf16

    // ---- prep ----
    embed_bf16<<<4096, 256, 0, stream>>>(src, enc_emb, embE, SRCL * BATCH);
    embed_bf16<<<3008, 256, 0, stream>>>(trg, dec_emb, embD, (TRGL - 1) * BATCH);
    zero_kernel<<<4096, 256, 0, stream>>>(zbase, 1048576);     // h0,h1,cbuf
    bias_prep<<<8, 256, 0, stream>>>(bih_f, bhh_f, bih_b, bhh_b, dec_bih, dec_bhh,
                                     bias_f, bias_b, bias_d);
    wcat_bf16<<<768, 256, 0, stream>>>(Wih_f, Whh_f, WcF);
    wcat_bf16<<<768, 256, 0, stream>>>(Wih_b, Whh_b, WcB);
    decw_bf16<<<256, 256, 0, stream>>>(dec_Wih, decWe);
    wdcat_bf16<<<1536, 256, 0, stream>>>(dec_Wih, dec_Whh, WdC);
    conv_f2b<<<256, 256, 0, stream>>>(fc_h_W, fcWh, 65536);
    conv_f2b<<<256, 256, 0, stream>>>(fc_c_W, fcWc, 65536);
    fo_pad<<<32, 256, 0, stream>>>(fc_out_W, foWb);

    // ---- encoder scan: 64 fused MFMA steps, h ping-pong ----
    for (int t = 0; t < SRCL; ++t) {
        const __bf16* hp = (t & 1) ? h1 : h0;
        __bf16*       hn = (t & 1) ? h0 : h1;
        enc_step_v3<<<dim3(32, 8, 2), 256, 0, stream>>>(
            embE, hp, hn, cbuf, es, WcF, WcB, bias_f, bias_b, t);
    }

    // ---- hidden projections (bf16 MFMA) ----
    cat_hfb<<<256, 256, 0, stream>>>(es, hfb);
    cat_cfb<<<256, 256, 0, stream>>>(cbuf, cfb);
    gmm_bf16<<<dim3(8, 8), 256, 0, stream>>>(hfb, fcWh, 1024, fc_h_b, hid_h, HSZ, HSZ);
    gmm_bf16<<<dim3(8, 8), 256, 0, stream>>>(cfb, fcWc, 1024, fc_c_b, hid_c, HSZ, HSZ);

    // ---- attention ----
    eh_kernel<<<128, 256, 0, stream>>>(hid_h, energy_W, energy_b, ehv);
    energy_kernel<<<8192, 256, 0, stream>>>(es, energy_W + HSZ, ehv, energy);
    softmax_kernel<<<128, 256, 0, stream>>>(energy, attn);
    context_kernel<<<512, 256, 0, stream>>>(attn, es, ctx);

    // ---- decoder batch-invariant part: D0 = [ctx|hid_h] @ [Wih(:,:1024)|Whh]^T + bias ----
    cat_ctxh<<<384, 256, 0, stream>>>(ctx, hid_h, ctxh);
    gmm_bf16<<<dim3(32, 8), 256, 0, stream>>>(ctxh, WdC, 1536, bias_d, D0, G4, G4);

    // ---- decoder fused gates + pointwise -> h_new (bf16) ----
    dec_mfma<<<dim3(16, 376), 256, 0, stream>>>(embD, decWe, D0, hid_c, h_new);

    // ---- outputs ----
    zero_kernel<<<134, 256, 0, stream>>>(out, BATCH * ODIM);
    gmm_bf16<<<dim3(2, 376), 256, 0, stream>>>(h_new, foWb, HSZ, fc_out_b,
                                               out + (size_t)BATCH * ODIM, ODIM, ODIM);
}